// Round 4
// baseline (691.349 us; speedup 1.0000x reference)
//
#include <hip/hip_runtime.h>

#define L_LAYERS 6
#define DMODEL 512
#define FFDIM 2048
#define NHEAD 8
#define SEQ 1024
#define BATCH 4
#define DHEAD 64
#define MROWS (BATCH*SEQ)   /* 4096 */

typedef __attribute__((ext_vector_type(4))) float f32x4;
typedef __attribute__((ext_vector_type(8))) unsigned short u16x8;
typedef __attribute__((ext_vector_type(8))) __bf16 bf16x8;

#define DEV static __device__ __forceinline__

DEV unsigned short f32_to_bf16(float f) {
  unsigned int u = __float_as_uint(f);
  u += 0x7fffu + ((u >> 16) & 1u);
  return (unsigned short)(u >> 16);
}
DEV float bf16_to_f32(unsigned short h) {
  return __uint_as_float(((unsigned int)h) << 16);
}
DEV f32x4 mfma_bf16(u16x8 a, u16x8 b, f32x4 c) {
  return __builtin_amdgcn_mfma_f32_16x16x32_bf16(
      __builtin_bit_cast(bf16x8, a), __builtin_bit_cast(bf16x8, b), c, 0, 0, 0);
}
// async global->LDS, 16B per lane; lds base must be wave-uniform
DEV void gload16(const unsigned short* g, unsigned short* l) {
  __builtin_amdgcn_global_load_lds(
      (const __attribute__((address_space(1))) unsigned int*)g,
      (__attribute__((address_space(3))) unsigned int*)l, 16, 0, 0);
}

// ---------------- add positional + transpose (S,B,D)->(B,S,D) ----------------
__global__ __launch_bounds__(256) void k_addpos(const float* __restrict__ src,
                                                const float* __restrict__ pos,
                                                float* __restrict__ x) {
  int gid = blockIdx.x * 256 + threadIdx.x;      // over S*B*D/4
  int d4 = gid & (DMODEL/4 - 1);
  int sb = gid >> 7;            // s*B + b
  int b  = sb & (BATCH-1);
  int s  = sb >> 2;
  f32x4 a = ((const f32x4*)src)[gid];
  f32x4 p = ((const f32x4*)pos)[gid];
  f32x4 r = a + p;
  ((f32x4*)x)[(size_t)(b*SEQ + s) * (DMODEL/4) + d4] = r;
}

// ---------------- weight transpose + bf16 convert:  [K][N] f32 -> [N][K] bf16 ----------------
__global__ __launch_bounds__(256) void k_transpose(const float* __restrict__ Win,
                                                   unsigned short* __restrict__ Wout,
                                                   int K, int N) {
  __shared__ float t[32][33];
  Win  += (size_t)blockIdx.z * K * N;
  Wout += (size_t)blockIdx.z * K * N;
  int n0 = blockIdx.x * 32, k0 = blockIdx.y * 32;
  int lx = threadIdx.x & 31, ly = threadIdx.x >> 5;   // 32 x 8
  #pragma unroll
  for (int r = 0; r < 32; r += 8)
    t[ly + r][lx] = Win[(size_t)(k0 + ly + r) * N + n0 + lx];
  __syncthreads();
  #pragma unroll
  for (int r = 0; r < 32; r += 8)
    Wout[(size_t)(n0 + ly + r) * K + k0 + lx] = f32_to_bf16(t[lx][ly + r]);
}

// ---------------- LayerNorm -> bf16 ----------------
__global__ __launch_bounds__(256) void k_ln_bf16(const float* __restrict__ x,
                                                 const float* __restrict__ g,
                                                 const float* __restrict__ be,
                                                 unsigned short* __restrict__ o) {
  int lane = threadIdx.x & 63, wv = threadIdx.x >> 6;
  int row = blockIdx.x * 4 + wv;
  const float* xr = x + (size_t)row * DMODEL + lane * 8;
  f32x4 v0 = *(const f32x4*)xr, v1 = *(const f32x4*)(xr + 4);
  float s  = v0.x+v0.y+v0.z+v0.w + v1.x+v1.y+v1.z+v1.w;
  float s2 = v0.x*v0.x+v0.y*v0.y+v0.z*v0.z+v0.w*v0.w
           + v1.x*v1.x+v1.y*v1.y+v1.z*v1.z+v1.w*v1.w;
  #pragma unroll
  for (int off = 1; off < 64; off <<= 1) { s += __shfl_xor(s, off); s2 += __shfl_xor(s2, off); }
  float mean = s * (1.0f/DMODEL);
  float var  = s2 * (1.0f/DMODEL) - mean*mean;
  float rs = rsqrtf(var + 1e-5f);
  const float* gp = g + lane*8; const float* bp = be + lane*8;
  f32x4 g0 = *(const f32x4*)gp, g1 = *(const f32x4*)(gp+4);
  f32x4 b0 = *(const f32x4*)bp, b1v = *(const f32x4*)(bp+4);
  u16x8 r;
  r[0] = f32_to_bf16((v0.x-mean)*rs*g0.x + b0.x);
  r[1] = f32_to_bf16((v0.y-mean)*rs*g0.y + b0.y);
  r[2] = f32_to_bf16((v0.z-mean)*rs*g0.z + b0.z);
  r[3] = f32_to_bf16((v0.w-mean)*rs*g0.w + b0.w);
  r[4] = f32_to_bf16((v1.x-mean)*rs*g1.x + b1v.x);
  r[5] = f32_to_bf16((v1.y-mean)*rs*g1.y + b1v.y);
  r[6] = f32_to_bf16((v1.z-mean)*rs*g1.z + b1v.z);
  r[7] = f32_to_bf16((v1.w-mean)*rs*g1.w + b1v.w);
  *(u16x8*)(o + (size_t)row * DMODEL + lane * 8) = r;
}

// ---------------- final LayerNorm, f32 out, (B,S,D)->(S,B,D) ----------------
__global__ __launch_bounds__(256) void k_ln_final(const float* __restrict__ x,
                                                  const float* __restrict__ g,
                                                  const float* __restrict__ be,
                                                  float* __restrict__ out) {
  int lane = threadIdx.x & 63, wv = threadIdx.x >> 6;
  int row = blockIdx.x * 4 + wv;     // row = b*S + s
  const float* xr = x + (size_t)row * DMODEL + lane * 8;
  f32x4 v0 = *(const f32x4*)xr, v1 = *(const f32x4*)(xr + 4);
  float s  = v0.x+v0.y+v0.z+v0.w + v1.x+v1.y+v1.z+v1.w;
  float s2 = v0.x*v0.x+v0.y*v0.y+v0.z*v0.z+v0.w*v0.w
           + v1.x*v1.x+v1.y*v1.y+v1.z*v1.z+v1.w*v1.w;
  #pragma unroll
  for (int off = 1; off < 64; off <<= 1) { s += __shfl_xor(s, off); s2 += __shfl_xor(s2, off); }
  float mean = s * (1.0f/DMODEL);
  float var  = s2 * (1.0f/DMODEL) - mean*mean;
  float rs = rsqrtf(var + 1e-5f);
  const float* gp = g + lane*8; const float* bp = be + lane*8;
  f32x4 g0 = *(const f32x4*)gp, g1 = *(const f32x4*)(gp+4);
  f32x4 b0 = *(const f32x4*)bp, b1v = *(const f32x4*)(bp+4);
  int b = row >> 10, ss = row & (SEQ-1);
  float* orow = out + (size_t)(ss*BATCH + b) * DMODEL + lane * 8;
  f32x4 o0, o1;
  o0.x = (v0.x-mean)*rs*g0.x + b0.x;  o0.y = (v0.y-mean)*rs*g0.y + b0.y;
  o0.z = (v0.z-mean)*rs*g0.z + b0.z;  o0.w = (v0.w-mean)*rs*g0.w + b0.w;
  o1.x = (v1.x-mean)*rs*g1.x + b1v.x; o1.y = (v1.y-mean)*rs*g1.y + b1v.y;
  o1.z = (v1.z-mean)*rs*g1.z + b1v.z; o1.w = (v1.w-mean)*rs*g1.w + b1v.w;
  *(f32x4*)orow = o0;
  *(f32x4*)(orow + 4) = o1;
}

// ---------------- GEMM core: A[M][K] bf16 x Bt[N][K] bf16, 128x128/block ----------------
// global_load_lds width-16 staging into LINEAR LDS tiles [128][32] (m97 pattern).
#define BM 128
#define BN 128
#define BKK 32

DEV void gemm_core(const unsigned short* __restrict__ A,
                   const unsigned short* __restrict__ Bt,
                   int K, int m0, int n0,
                   unsigned short* As, unsigned short* Bs, f32x4 acc[4][4]) {
  const int tid = threadIdx.x;
  const int lane = tid & 63;
  const int w = tid >> 6;
  const int wr = w >> 1, wc = w & 1;
  const int l15 = lane & 15;
  const int ko = (lane >> 4) * 8;
  const int rl = lane >> 2;            // 0..15: row within 16-row chunk
  const int cc = (lane & 3) * 8;       // col within 32-wide k slab
  for (int kb = 0; kb < K; kb += BKK) {
    #pragma unroll
    for (int i = 0; i < 2; ++i) {
      int r0 = w * 32 + i * 16;        // wave-uniform chunk base
      gload16(A  + (size_t)(m0 + r0 + rl) * K + kb + cc, As + r0 * BKK);
      gload16(Bt + (size_t)(n0 + r0 + rl) * K + kb + cc, Bs + r0 * BKK);
    }
    __syncthreads();
    u16x8 af[4], bfr[4];
    #pragma unroll
    for (int m = 0; m < 4; ++m) af[m]  = *(const u16x8*)(As + (wr*64 + m*16 + l15) * BKK + ko);
    #pragma unroll
    for (int n = 0; n < 4; ++n) bfr[n] = *(const u16x8*)(Bs + (wc*64 + n*16 + l15) * BKK + ko);
    #pragma unroll
    for (int m = 0; m < 4; ++m)
      #pragma unroll
      for (int n = 0; n < 4; ++n)
        acc[m][n] = mfma_bf16(af[m], bfr[n], acc[m][n]);
    __syncthreads();
  }
}

// ---------------- QKV fused GEMM; Q,K -> [B,H,S,DH], V -> transposed [B,H,DH,S] ----------------
__global__ __launch_bounds__(256) void k_gemm_qkv(
    const unsigned short* __restrict__ x1,
    const unsigned short* __restrict__ WqT, const unsigned short* __restrict__ WkT,
    const unsigned short* __restrict__ WvT,
    const float* __restrict__ bq, const float* __restrict__ bk, const float* __restrict__ bv,
    unsigned short* __restrict__ qo, unsigned short* __restrict__ ko2,
    unsigned short* __restrict__ vo) {
  __shared__ __align__(16) unsigned short As[BM*BKK];
  __shared__ __align__(16) unsigned short Bs[BN*BKK];
  int m0 = blockIdx.x * BM;
  int mat = blockIdx.y >> 2;
  int n0 = (blockIdx.y & 3) * BN;
  const unsigned short* Bt = (mat == 0) ? WqT : ((mat == 1) ? WkT : WvT);
  const float* bias        = (mat == 0) ? bq  : ((mat == 1) ? bk  : bv);
  unsigned short* out      = (mat == 0) ? qo  : ((mat == 1) ? ko2 : vo);
  f32x4 acc[4][4];
  #pragma unroll
  for (int m = 0; m < 4; ++m)
    #pragma unroll
    for (int n = 0; n < 4; ++n) acc[m][n] = 0.0f;
  gemm_core(x1, Bt, DMODEL, m0, n0, As, Bs, acc);
  const int lane = threadIdx.x & 63;
  const int w = threadIdx.x >> 6; const int wr = w >> 1, wc = w & 1;
  #pragma unroll
  for (int m = 0; m < 4; ++m) {
    #pragma unroll
    for (int n = 0; n < 4; ++n) {
      int col = n0 + wc*64 + n*16 + (lane & 15);
      int hh = col >> 6, dh = col & 63;
      float bval = bias[col];
      #pragma unroll
      for (int i = 0; i < 4; ++i) {
        int row = m0 + wr*64 + m*16 + (lane >> 4)*4 + i;
        int bb = row >> 10, ss = row & (SEQ-1);
        size_t oidx;
        if (mat == 2)
          oidx = ((((size_t)(bb*NHEAD + hh)) * DHEAD + dh) << 10) + ss;   // V^T: [B,H,DH,S]
        else
          oidx = ((((size_t)(bb*NHEAD + hh)) << 10) + ss) * DHEAD + dh;   // [B,H,S,DH]
        out[oidx] = f32_to_bf16(acc[m][n][i] + bval);
      }
    }
  }
}

// ---------------- FFN1: relu(x1 @ W1 + b1) -> bf16 h ----------------
__global__ __launch_bounds__(256) void k_gemm_ffn1(
    const unsigned short* __restrict__ x1, const unsigned short* __restrict__ W1T,
    const float* __restrict__ b1, unsigned short* __restrict__ h) {
  __shared__ __align__(16) unsigned short As[BM*BKK];
  __shared__ __align__(16) unsigned short Bs[BN*BKK];
  int m0 = blockIdx.x * BM, n0 = blockIdx.y * BN;
  f32x4 acc[4][4];
  #pragma unroll
  for (int m = 0; m < 4; ++m)
    #pragma unroll
    for (int n = 0; n < 4; ++n) acc[m][n] = 0.0f;
  gemm_core(x1, W1T, DMODEL, m0, n0, As, Bs, acc);
  const int lane = threadIdx.x & 63;
  const int w = threadIdx.x >> 6; const int wr = w >> 1, wc = w & 1;
  #pragma unroll
  for (int m = 0; m < 4; ++m) {
    #pragma unroll
    for (int n = 0; n < 4; ++n) {
      int col = n0 + wc*64 + n*16 + (lane & 15);
      float bval = b1[col];
      #pragma unroll
      for (int i = 0; i < 4; ++i) {
        int row = m0 + wr*64 + m*16 + (lane >> 4)*4 + i;
        h[(size_t)row * FFDIM + col] = f32_to_bf16(fmaxf(acc[m][n][i] + bval, 0.0f));
      }
    }
  }
}

// ---------------- FFN2: x += h @ W2 + b2  (64x64 tiles -> 512 blocks) ----------------
__global__ __launch_bounds__(256) void k_gemm_ffn2(
    const unsigned short* __restrict__ h, const unsigned short* __restrict__ W2T,
    const float* __restrict__ b2, float* __restrict__ x) {
  __shared__ __align__(16) unsigned short As[64*BKK];
  __shared__ __align__(16) unsigned short Bs[64*BKK];
  const int tid = threadIdx.x;
  const int lane = tid & 63;
  const int w = tid >> 6;
  const int wr = w >> 1, wc = w & 1;
  const int l15 = lane & 15;
  const int ko = (lane >> 4) * 8;
  const int rl = lane >> 2;
  const int cc = (lane & 3) * 8;
  const int m0 = blockIdx.x * 64, n0 = blockIdx.y * 64;
  f32x4 acc[2][2];
  #pragma unroll
  for (int m = 0; m < 2; ++m)
    #pragma unroll
    for (int n = 0; n < 2; ++n) acc[m][n] = 0.0f;
  for (int kb = 0; kb < FFDIM; kb += BKK) {
    int r0 = w * 16;                   // wave-uniform 16-row chunk
    gload16(h   + (size_t)(m0 + r0 + rl) * FFDIM + kb + cc, As + r0 * BKK);
    gload16(W2T + (size_t)(n0 + r0 + rl) * FFDIM + kb + cc, Bs + r0 * BKK);
    __syncthreads();
    u16x8 af[2], bfr[2];
    #pragma unroll
    for (int m = 0; m < 2; ++m) af[m]  = *(const u16x8*)(As + (wr*32 + m*16 + l15) * BKK + ko);
    #pragma unroll
    for (int n = 0; n < 2; ++n) bfr[n] = *(const u16x8*)(Bs + (wc*32 + n*16 + l15) * BKK + ko);
    #pragma unroll
    for (int m = 0; m < 2; ++m)
      #pragma unroll
      for (int n = 0; n < 2; ++n)
        acc[m][n] = mfma_bf16(af[m], bfr[n], acc[m][n]);
    __syncthreads();
  }
  const int g = lane >> 4;
  #pragma unroll
  for (int m = 0; m < 2; ++m) {
    #pragma unroll
    for (int n = 0; n < 2; ++n) {
      int col = n0 + wc*32 + n*16 + l15;
      float bval = b2[col];
      #pragma unroll
      for (int i = 0; i < 4; ++i) {
        int row = m0 + wr*32 + m*16 + g*4 + i;
        size_t idx = (size_t)row * DMODEL + col;
        x[idx] = x[idx] + acc[m][n][i] + bval;
      }
    }
  }
}

// ---------------- MFMA flash attention, kv-split x2: partials to ws ----------------
#define KVBLK 64
#define KP 72   /* LDS pitch (ushorts): 144B -> 2-way conflicts only */

__global__ __launch_bounds__(256) void k_attn_split(
    const unsigned short* __restrict__ qb,   // [BH][S][DH]
    const unsigned short* __restrict__ kb,   // [BH][S][DH]
    const unsigned short* __restrict__ vtb,  // [BH][DH][S]
    float* __restrict__ accP,                // [2][BH][S][DH]
    float* __restrict__ mP, float* __restrict__ lP) {  // [2][BH][S]
  __shared__ __align__(16) unsigned short Kl[KVBLK*KP];
  __shared__ __align__(16) unsigned short Vl[DHEAD*KP];     // V^T tile: [dh][kv]
  __shared__ __align__(16) unsigned short Pl[4*16*KP];
  const int tid = threadIdx.x;
  const int w = tid >> 6, lane = tid & 63;
  const int c = lane & 15, g = lane >> 4;
  const int bh = blockIdx.x, qt = blockIdx.y, kp = blockIdx.z;
  const int qw = qt * 64 + w * 16;          // this wave's first q row

  u16x8 qf[2];
  {
    const unsigned short* qrow = qb + ((size_t)bh * SEQ + qw + c) * DHEAD;
    qf[0] = *(const u16x8*)(qrow + g * 8);
    qf[1] = *(const u16x8*)(qrow + 32 + g * 8);
  }
  f32x4 aco[4];
  #pragma unroll
  for (int n = 0; n < 4; ++n) aco[n] = 0.0f;
  float m_i[4] = {-1e30f, -1e30f, -1e30f, -1e30f};
  float l_i[4] = {0.f, 0.f, 0.f, 0.f};

  const unsigned short* kbase = kb + (size_t)bh * SEQ * DHEAD;
  const unsigned short* vbase = vtb + (size_t)bh * DHEAD * SEQ;

  const int kv_lo = kp * (SEQ/2), kv_hi = kv_lo + SEQ/2;
  for (int kv0 = kv_lo; kv0 < kv_hi; kv0 += KVBLK) {
    #pragma unroll
    for (int i = 0; i < 2; ++i) {
      int idx = tid + i * 256;
      int r = idx >> 3, cb = (idx & 7) * 8;
      *(u16x8*)(Kl + r * KP + cb) = *(const u16x8*)(kbase + (size_t)(kv0 + r) * DHEAD + cb);
      *(u16x8*)(Vl + r * KP + cb) = *(const u16x8*)(vbase + (size_t)r * SEQ + kv0 + cb);
    }
    __syncthreads();

    f32x4 s[4];
    #pragma unroll
    for (int n = 0; n < 4; ++n) s[n] = 0.0f;
    #pragma unroll
    for (int n = 0; n < 4; ++n) {
      #pragma unroll
      for (int kk = 0; kk < 2; ++kk) {
        u16x8 kf = *(const u16x8*)(Kl + (n * 16 + c) * KP + kk * 32 + g * 8);
        s[n] = mfma_bf16(qf[kk], kf, s[n]);
      }
    }

    float corr_i[4];
    #pragma unroll
    for (int i = 0; i < 4; ++i) {
      float v0 = s[0][i] * 0.125f, v1 = s[1][i] * 0.125f;
      float v2 = s[2][i] * 0.125f, v3 = s[3][i] * 0.125f;
      float mx = fmaxf(fmaxf(v0, v1), fmaxf(v2, v3));
      mx = fmaxf(mx, __shfl_xor(mx, 1));
      mx = fmaxf(mx, __shfl_xor(mx, 2));
      mx = fmaxf(mx, __shfl_xor(mx, 4));
      mx = fmaxf(mx, __shfl_xor(mx, 8));
      float mn = fmaxf(m_i[i], mx);
      corr_i[i] = __expf(m_i[i] - mn);
      float p0 = __expf(v0 - mn), p1 = __expf(v1 - mn);
      float p2 = __expf(v2 - mn), p3 = __expf(v3 - mn);
      float ps = (p0 + p1) + (p2 + p3);
      ps += __shfl_xor(ps, 1);
      ps += __shfl_xor(ps, 2);
      ps += __shfl_xor(ps, 4);
      ps += __shfl_xor(ps, 8);
      l_i[i] = l_i[i] * corr_i[i] + ps;
      m_i[i] = mn;
      int prow = (w * 16 + g * 4 + i) * KP + c;
      Pl[prow]      = f32_to_bf16(p0);
      Pl[prow + 16] = f32_to_bf16(p1);
      Pl[prow + 32] = f32_to_bf16(p2);
      Pl[prow + 48] = f32_to_bf16(p3);
    }
    #pragma unroll
    for (int n = 0; n < 4; ++n)
      #pragma unroll
      for (int i = 0; i < 4; ++i) aco[n][i] *= corr_i[i];

    u16x8 pa[2];
    pa[0] = *(const u16x8*)(Pl + (w * 16 + c) * KP + g * 8);
    pa[1] = *(const u16x8*)(Pl + (w * 16 + c) * KP + 32 + g * 8);
    #pragma unroll
    for (int n = 0; n < 4; ++n) {
      #pragma unroll
      for (int kk = 0; kk < 2; ++kk) {
        u16x8 vf = *(const u16x8*)(Vl + (n * 16 + c) * KP + kk * 32 + g * 8);
        aco[n] = mfma_bf16(pa[kk], vf, aco[n]);
      }
    }
    __syncthreads();
  }

  // epilogue: write raw partial ctx + m,l
  #pragma unroll
  for (int i = 0; i < 4; ++i) {
    int q = qw + g * 4 + i;
    size_t pidx = (((size_t)kp * 32 + bh) << 10) + q;
    float* ap = accP + pidx * DHEAD;
    #pragma unroll
    for (int n = 0; n < 4; ++n)
      ap[n * 16 + c] = aco[n][i];
    if (c == 0) { mP[pidx] = m_i[i]; lP[pidx] = l_i[i]; }
  }
}

// ---------------- combine 2 kv-split partials, add into x ----------------
__global__ __launch_bounds__(256) void k_combine(const float* __restrict__ accP,
                                                 const float* __restrict__ mP,
                                                 const float* __restrict__ lP,
                                                 float* __restrict__ x) {
  int gid = blockIdx.x * 256 + threadIdx.x;  // over 32768*16
  int qg = gid >> 4, d4 = gid & 15;
  int bh = qg >> 10, qi = qg & (SEQ-1);
  float m1 = mP[qg], m2 = mP[32768 + qg];
  float l1 = lP[qg], l2 = lP[32768 + qg];
  float mm = fmaxf(m1, m2);
  float w1 = __expf(m1 - mm), w2 = __expf(m2 - mm);
  float den = l1*w1 + l2*w2;
  f32x4 a1 = *(const f32x4*)(accP + (size_t)qg*DHEAD + d4*4);
  f32x4 a2 = *(const f32x4*)(accP + ((size_t)32768 + qg)*DHEAD + d4*4);
  f32x4 ctx = (a1*w1 + a2*w2) * (1.0f/den);
  float* xp = x + ((size_t)(bh >> 3) * SEQ + qi) * DMODEL + (bh & 7) * DHEAD + d4*4;
  f32x4 xv = *(f32x4*)xp;
  *(f32x4*)xp = xv + ctx;
}

// ---------------- host launch ----------------
extern "C" void kernel_launch(void* const* d_in, const int* in_sizes, int n_in,
                              void* d_out, int out_size, void* d_ws, size_t ws_size,
                              hipStream_t stream) {
  const float* src  = (const float*)d_in[0];
  const float* pos  = (const float*)d_in[1];
  const float* Wq   = (const float*)d_in[2];
  const float* bq   = (const float*)d_in[3];
  const float* Wk   = (const float*)d_in[4];
  const float* bk   = (const float*)d_in[5];
  const float* Wv   = (const float*)d_in[6];
  const float* bv   = (const float*)d_in[7];
  const float* W1   = (const float*)d_in[8];
  const float* b1   = (const float*)d_in[9];
  const float* W2   = (const float*)d_in[10];
  const float* b2   = (const float*)d_in[11];
  const float* ln1g = (const float*)d_in[12];
  const float* ln1b = (const float*)d_in[13];
  const float* ln2g = (const float*)d_in[14];
  const float* ln2b = (const float*)d_in[15];
  const float* lnfg = (const float*)d_in[16];
  const float* lnfb = (const float*)d_in[17];

  char* p = (char*)d_ws;
  float* x = (float*)p;                      p += (size_t)MROWS * DMODEL * 4;   // 8 MB
  unsigned short* x1 = (unsigned short*)p;   p += (size_t)MROWS * DMODEL * 2;   // 4 MB
  unsigned short* qb = (unsigned short*)p;   p += (size_t)MROWS * DMODEL * 2;
  unsigned short* kbuf = (unsigned short*)p; p += (size_t)MROWS * DMODEL * 2;
  unsigned short* vtbuf = (unsigned short*)p; p += (size_t)MROWS * DMODEL * 2;  // V^T [B,H,DH,S]
  unsigned short* hbuf = (unsigned short*)p; p += (size_t)MROWS * FFDIM * 2;    // 16 MB
  float* accP = (float*)hbuf;                // aliases hbuf: attn partials die before ffn1
  unsigned short* WqT = (unsigned short*)p;  p += (size_t)L_LAYERS * DMODEL * DMODEL * 2;
  unsigned short* WkT = (unsigned short*)p;  p += (size_t)L_LAYERS * DMODEL * DMODEL * 2;
  unsigned short* WvT = (unsigned short*)p;  p += (size_t)L_LAYERS * DMODEL * DMODEL * 2;
  unsigned short* W1T = (unsigned short*)p;  p += (size_t)L_LAYERS * DMODEL * FFDIM * 2;
  unsigned short* W2T = (unsigned short*)p;  p += (size_t)L_LAYERS * DMODEL * FFDIM * 2;
  float* mP = (float*)p;                     p += (size_t)2 * 32768 * 4;
  float* lP = (float*)p;                     p += (size_t)2 * 32768 * 4;

  // one-time weight transpose+convert
  k_transpose<<<dim3(16,16,6), 256, 0, stream>>>(Wq, WqT, DMODEL, DMODEL);
  k_transpose<<<dim3(16,16,6), 256, 0, stream>>>(Wk, WkT, DMODEL, DMODEL);
  k_transpose<<<dim3(16,16,6), 256, 0, stream>>>(Wv, WvT, DMODEL, DMODEL);
  k_transpose<<<dim3(64,16,6), 256, 0, stream>>>(W1, W1T, DMODEL, FFDIM);
  k_transpose<<<dim3(16,64,6), 256, 0, stream>>>(W2, W2T, FFDIM, DMODEL);

  k_addpos<<<2048, 256, 0, stream>>>(src, pos, x);

  for (int l = 0; l < L_LAYERS; ++l) {
    k_ln_bf16<<<1024, 256, 0, stream>>>(x, ln1g + l*DMODEL, ln1b + l*DMODEL, x1);
    k_gemm_qkv<<<dim3(32,12), 256, 0, stream>>>(
        x1,
        WqT + (size_t)l*DMODEL*DMODEL, WkT + (size_t)l*DMODEL*DMODEL, WvT + (size_t)l*DMODEL*DMODEL,
        bq + l*DMODEL, bk + l*DMODEL, bv + l*DMODEL,
        qb, kbuf, vtbuf);
    k_attn_split<<<dim3(32,16,2), 256, 0, stream>>>(qb, kbuf, vtbuf, accP, mP, lP);
    k_combine<<<2048, 256, 0, stream>>>(accP, mP, lP, x);
    k_ln_bf16<<<1024, 256, 0, stream>>>(x, ln2g + l*DMODEL, ln2b + l*DMODEL, x1);
    k_gemm_ffn1<<<dim3(32,16), 256, 0, stream>>>(x1, W1T + (size_t)l*DMODEL*FFDIM, b1 + l*FFDIM, hbuf);
    k_gemm_ffn2<<<dim3(64,8), 256, 0, stream>>>(hbuf, W2T + (size_t)l*DMODEL*FFDIM, b2 + l*DMODEL, x);
  }
  k_ln_final<<<1024, 256, 0, stream>>>(x, lnfg, lnfb, (float*)d_out);
}

// Round 5
// 638.003 us; speedup vs baseline: 1.0836x; 1.0836x over previous
//
#include <hip/hip_runtime.h>

#define L_LAYERS 6
#define DMODEL 512
#define FFDIM 2048
#define NHEAD 8
#define SEQ 1024
#define BATCH 4
#define DHEAD 64
#define MROWS (BATCH*SEQ)   /* 4096 */

typedef __attribute__((ext_vector_type(4))) float f32x4;
typedef __attribute__((ext_vector_type(8))) unsigned short u16x8;
typedef __attribute__((ext_vector_type(8))) __bf16 bf16x8;

#define DEV static __device__ __forceinline__

DEV unsigned short f32_to_bf16(float f) {
  unsigned int u = __float_as_uint(f);
  u += 0x7fffu + ((u >> 16) & 1u);
  return (unsigned short)(u >> 16);
}
DEV float bf16_to_f32(unsigned short h) {
  return __uint_as_float(((unsigned int)h) << 16);
}
DEV f32x4 mfma_bf16(u16x8 a, u16x8 b, f32x4 c) {
  return __builtin_amdgcn_mfma_f32_16x16x32_bf16(
      __builtin_bit_cast(bf16x8, a), __builtin_bit_cast(bf16x8, b), c, 0, 0, 0);
}
// async global->LDS, 16B per lane; lds base must be wave-uniform
DEV void gload16(const unsigned short* g, unsigned short* l) {
  __builtin_amdgcn_global_load_lds(
      (const __attribute__((address_space(1))) unsigned int*)g,
      (__attribute__((address_space(3))) unsigned int*)l, 16, 0, 0);
}

// ---------------- weight transpose + bf16 convert:  [K][N] f32 -> [N][K] bf16 ----------------
__global__ __launch_bounds__(256) void k_transpose(const float* __restrict__ Win,
                                                   unsigned short* __restrict__ Wout,
                                                   int K, int N) {
  __shared__ float t[32][33];
  Win  += (size_t)blockIdx.z * K * N;
  Wout += (size_t)blockIdx.z * K * N;
  int n0 = blockIdx.x * 32, k0 = blockIdx.y * 32;
  int lx = threadIdx.x & 31, ly = threadIdx.x >> 5;   // 32 x 8
  #pragma unroll
  for (int r = 0; r < 32; r += 8)
    t[ly + r][lx] = Win[(size_t)(k0 + ly + r) * N + n0 + lx];
  __syncthreads();
  #pragma unroll
  for (int r = 0; r < 32; r += 8)
    Wout[(size_t)(n0 + ly + r) * K + k0 + lx] = f32_to_bf16(t[lx][ly + r]);
}

// ---------------- fused addpos + LN (layer 0): x = src+pos (transposed), x1 = LN(x) ----------------
__global__ __launch_bounds__(256) void k_addpos_ln(const float* __restrict__ src,
                                                   const float* __restrict__ pos,
                                                   const float* __restrict__ g,
                                                   const float* __restrict__ be,
                                                   float* __restrict__ x,
                                                   unsigned short* __restrict__ o) {
  int lane = threadIdx.x & 63, wv = threadIdx.x >> 6;
  int row = blockIdx.x * 4 + wv;        // row = b*S + s
  int b = row >> 10, ss = row & (SEQ-1);
  const float* sr = src + (size_t)(ss*BATCH + b) * DMODEL + lane * 8;
  const float* pr = pos + (size_t)(ss*BATCH + b) * DMODEL + lane * 8;
  f32x4 v0 = *(const f32x4*)sr + *(const f32x4*)pr;
  f32x4 v1 = *(const f32x4*)(sr + 4) + *(const f32x4*)(pr + 4);
  float* xr = x + (size_t)row * DMODEL + lane * 8;
  *(f32x4*)xr = v0;
  *(f32x4*)(xr + 4) = v1;
  float s  = v0.x+v0.y+v0.z+v0.w + v1.x+v1.y+v1.z+v1.w;
  float s2 = v0.x*v0.x+v0.y*v0.y+v0.z*v0.z+v0.w*v0.w
           + v1.x*v1.x+v1.y*v1.y+v1.z*v1.z+v1.w*v1.w;
  #pragma unroll
  for (int off = 1; off < 64; off <<= 1) { s += __shfl_xor(s, off); s2 += __shfl_xor(s2, off); }
  float mean = s * (1.0f/DMODEL);
  float var  = s2 * (1.0f/DMODEL) - mean*mean;
  float rs = rsqrtf(var + 1e-5f);
  const float* gp = g + lane*8; const float* bp = be + lane*8;
  f32x4 g0 = *(const f32x4*)gp, g1 = *(const f32x4*)(gp+4);
  f32x4 b0 = *(const f32x4*)bp, b1v = *(const f32x4*)(bp+4);
  u16x8 r;
  r[0] = f32_to_bf16((v0.x-mean)*rs*g0.x + b0.x);
  r[1] = f32_to_bf16((v0.y-mean)*rs*g0.y + b0.y);
  r[2] = f32_to_bf16((v0.z-mean)*rs*g0.z + b0.z);
  r[3] = f32_to_bf16((v0.w-mean)*rs*g0.w + b0.w);
  r[4] = f32_to_bf16((v1.x-mean)*rs*g1.x + b1v.x);
  r[5] = f32_to_bf16((v1.y-mean)*rs*g1.y + b1v.y);
  r[6] = f32_to_bf16((v1.z-mean)*rs*g1.z + b1v.z);
  r[7] = f32_to_bf16((v1.w-mean)*rs*g1.w + b1v.w);
  *(u16x8*)(o + (size_t)row * DMODEL + lane * 8) = r;
}

// ---------------- LayerNorm -> bf16 ----------------
__global__ __launch_bounds__(256) void k_ln_bf16(const float* __restrict__ x,
                                                 const float* __restrict__ g,
                                                 const float* __restrict__ be,
                                                 unsigned short* __restrict__ o) {
  int lane = threadIdx.x & 63, wv = threadIdx.x >> 6;
  int row = blockIdx.x * 4 + wv;
  const float* xr = x + (size_t)row * DMODEL + lane * 8;
  f32x4 v0 = *(const f32x4*)xr, v1 = *(const f32x4*)(xr + 4);
  float s  = v0.x+v0.y+v0.z+v0.w + v1.x+v1.y+v1.z+v1.w;
  float s2 = v0.x*v0.x+v0.y*v0.y+v0.z*v0.z+v0.w*v0.w
           + v1.x*v1.x+v1.y*v1.y+v1.z*v1.z+v1.w*v1.w;
  #pragma unroll
  for (int off = 1; off < 64; off <<= 1) { s += __shfl_xor(s, off); s2 += __shfl_xor(s2, off); }
  float mean = s * (1.0f/DMODEL);
  float var  = s2 * (1.0f/DMODEL) - mean*mean;
  float rs = rsqrtf(var + 1e-5f);
  const float* gp = g + lane*8; const float* bp = be + lane*8;
  f32x4 g0 = *(const f32x4*)gp, g1 = *(const f32x4*)(gp+4);
  f32x4 b0 = *(const f32x4*)bp, b1v = *(const f32x4*)(bp+4);
  u16x8 r;
  r[0] = f32_to_bf16((v0.x-mean)*rs*g0.x + b0.x);
  r[1] = f32_to_bf16((v0.y-mean)*rs*g0.y + b0.y);
  r[2] = f32_to_bf16((v0.z-mean)*rs*g0.z + b0.z);
  r[3] = f32_to_bf16((v0.w-mean)*rs*g0.w + b0.w);
  r[4] = f32_to_bf16((v1.x-mean)*rs*g1.x + b1v.x);
  r[5] = f32_to_bf16((v1.y-mean)*rs*g1.y + b1v.y);
  r[6] = f32_to_bf16((v1.z-mean)*rs*g1.z + b1v.z);
  r[7] = f32_to_bf16((v1.w-mean)*rs*g1.w + b1v.w);
  *(u16x8*)(o + (size_t)row * DMODEL + lane * 8) = r;
}

// ---------------- final LayerNorm, f32 out, (B,S,D)->(S,B,D) ----------------
__global__ __launch_bounds__(256) void k_ln_final(const float* __restrict__ x,
                                                  const float* __restrict__ g,
                                                  const float* __restrict__ be,
                                                  float* __restrict__ out) {
  int lane = threadIdx.x & 63, wv = threadIdx.x >> 6;
  int row = blockIdx.x * 4 + wv;     // row = b*S + s
  const float* xr = x + (size_t)row * DMODEL + lane * 8;
  f32x4 v0 = *(const f32x4*)xr, v1 = *(const f32x4*)(xr + 4);
  float s  = v0.x+v0.y+v0.z+v0.w + v1.x+v1.y+v1.z+v1.w;
  float s2 = v0.x*v0.x+v0.y*v0.y+v0.z*v0.z+v0.w*v0.w
           + v1.x*v1.x+v1.y*v1.y+v1.z*v1.z+v1.w*v1.w;
  #pragma unroll
  for (int off = 1; off < 64; off <<= 1) { s += __shfl_xor(s, off); s2 += __shfl_xor(s2, off); }
  float mean = s * (1.0f/DMODEL);
  float var  = s2 * (1.0f/DMODEL) - mean*mean;
  float rs = rsqrtf(var + 1e-5f);
  const float* gp = g + lane*8; const float* bp = be + lane*8;
  f32x4 g0 = *(const f32x4*)gp, g1 = *(const f32x4*)(gp+4);
  f32x4 b0 = *(const f32x4*)bp, b1v = *(const f32x4*)(bp+4);
  int b = row >> 10, ss = row & (SEQ-1);
  float* orow = out + (size_t)(ss*BATCH + b) * DMODEL + lane * 8;
  f32x4 o0, o1;
  o0.x = (v0.x-mean)*rs*g0.x + b0.x;  o0.y = (v0.y-mean)*rs*g0.y + b0.y;
  o0.z = (v0.z-mean)*rs*g0.z + b0.z;  o0.w = (v0.w-mean)*rs*g0.w + b0.w;
  o1.x = (v1.x-mean)*rs*g1.x + b1v.x; o1.y = (v1.y-mean)*rs*g1.y + b1v.y;
  o1.z = (v1.z-mean)*rs*g1.z + b1v.z; o1.w = (v1.w-mean)*rs*g1.w + b1v.w;
  *(f32x4*)orow = o0;
  *(f32x4*)(orow + 4) = o1;
}

// ---------------- GEMM core: A[M][K] bf16 x Bt[N][K] bf16, 128x128/block ----------------
#define BM 128
#define BN 128
#define BKK 32

DEV void gemm_core(const unsigned short* __restrict__ A,
                   const unsigned short* __restrict__ Bt,
                   int K, int m0, int n0,
                   unsigned short* As, unsigned short* Bs, f32x4 acc[4][4]) {
  const int tid = threadIdx.x;
  const int lane = tid & 63;
  const int w = tid >> 6;
  const int wr = w >> 1, wc = w & 1;
  const int l15 = lane & 15;
  const int ko = (lane >> 4) * 8;
  const int rl = lane >> 2;            // 0..15: row within 16-row chunk
  const int cc = (lane & 3) * 8;       // col within 32-wide k slab
  for (int kb = 0; kb < K; kb += BKK) {
    #pragma unroll
    for (int i = 0; i < 2; ++i) {
      int r0 = w * 32 + i * 16;        // wave-uniform chunk base
      gload16(A  + (size_t)(m0 + r0 + rl) * K + kb + cc, As + r0 * BKK);
      gload16(Bt + (size_t)(n0 + r0 + rl) * K + kb + cc, Bs + r0 * BKK);
    }
    __syncthreads();
    u16x8 af[4], bfr[4];
    #pragma unroll
    for (int m = 0; m < 4; ++m) af[m]  = *(const u16x8*)(As + (wr*64 + m*16 + l15) * BKK + ko);
    #pragma unroll
    for (int n = 0; n < 4; ++n) bfr[n] = *(const u16x8*)(Bs + (wc*64 + n*16 + l15) * BKK + ko);
    #pragma unroll
    for (int m = 0; m < 4; ++m)
      #pragma unroll
      for (int n = 0; n < 4; ++n)
        acc[m][n] = mfma_bf16(af[m], bfr[n], acc[m][n]);
    __syncthreads();
  }
}

// ---------------- QKV fused GEMM (128x64 tiles, grid 32x24 = 768 = 3/CU) ----------------
// Q,K -> [B,H,S,DH], V -> transposed [B,H,DH,S]
__global__ __launch_bounds__(256) void k_gemm_qkv(
    const unsigned short* __restrict__ x1,
    const unsigned short* __restrict__ WqT, const unsigned short* __restrict__ WkT,
    const unsigned short* __restrict__ WvT,
    const float* __restrict__ bq, const float* __restrict__ bk, const float* __restrict__ bv,
    unsigned short* __restrict__ qo, unsigned short* __restrict__ ko2,
    unsigned short* __restrict__ vo) {
  __shared__ __align__(16) unsigned short As[BM*BKK];
  __shared__ __align__(16) unsigned short Bs[64*BKK];
  const int tid = threadIdx.x;
  const int lane = tid & 63;
  const int w = tid >> 6;
  const int wr = w >> 1, wc = w & 1;
  const int l15 = lane & 15;
  const int ko = (lane >> 4) * 8;
  const int rl = lane >> 2;
  const int cc = (lane & 3) * 8;
  const int m0 = blockIdx.x * BM;
  const int mat = blockIdx.y >> 3;
  const int n0 = (blockIdx.y & 7) * 64;
  const unsigned short* Bt = (mat == 0) ? WqT : ((mat == 1) ? WkT : WvT);
  const float* bias        = (mat == 0) ? bq  : ((mat == 1) ? bk  : bv);
  unsigned short* out      = (mat == 0) ? qo  : ((mat == 1) ? ko2 : vo);
  f32x4 acc[4][2];
  #pragma unroll
  for (int m = 0; m < 4; ++m)
    #pragma unroll
    for (int n = 0; n < 2; ++n) acc[m][n] = 0.0f;
  for (int kb = 0; kb < DMODEL; kb += BKK) {
    #pragma unroll
    for (int i = 0; i < 2; ++i) {
      int r0 = w * 32 + i * 16;
      gload16(x1 + (size_t)(m0 + r0 + rl) * DMODEL + kb + cc, As + r0 * BKK);
    }
    {
      int r0 = w * 16;
      gload16(Bt + (size_t)(n0 + r0 + rl) * DMODEL + kb + cc, Bs + r0 * BKK);
    }
    __syncthreads();
    u16x8 af[4], bfr[2];
    #pragma unroll
    for (int m = 0; m < 4; ++m) af[m]  = *(const u16x8*)(As + (wr*64 + m*16 + l15) * BKK + ko);
    #pragma unroll
    for (int n = 0; n < 2; ++n) bfr[n] = *(const u16x8*)(Bs + (wc*32 + n*16 + l15) * BKK + ko);
    #pragma unroll
    for (int m = 0; m < 4; ++m)
      #pragma unroll
      for (int n = 0; n < 2; ++n)
        acc[m][n] = mfma_bf16(af[m], bfr[n], acc[m][n]);
    __syncthreads();
  }
  const int g = lane >> 4;
  #pragma unroll
  for (int m = 0; m < 4; ++m) {
    #pragma unroll
    for (int n = 0; n < 2; ++n) {
      int col = n0 + wc*32 + n*16 + l15;
      int hh = col >> 6, dh = col & 63;
      float bval = bias[col];
      #pragma unroll
      for (int i = 0; i < 4; ++i) {
        int row = m0 + wr*64 + m*16 + g*4 + i;
        int bb = row >> 10, ss = row & (SEQ-1);
        size_t oidx;
        if (mat == 2)
          oidx = ((((size_t)(bb*NHEAD + hh)) * DHEAD + dh) << 10) + ss;   // V^T: [B,H,DH,S]
        else
          oidx = ((((size_t)(bb*NHEAD + hh)) << 10) + ss) * DHEAD + dh;   // [B,H,S,DH]
        out[oidx] = f32_to_bf16(acc[m][n][i] + bval);
      }
    }
  }
}

// ---------------- FFN1: relu(x1 @ W1 + b1) -> bf16 h ----------------
__global__ __launch_bounds__(256) void k_gemm_ffn1(
    const unsigned short* __restrict__ x1, const unsigned short* __restrict__ W1T,
    const float* __restrict__ b1, unsigned short* __restrict__ h) {
  __shared__ __align__(16) unsigned short As[BM*BKK];
  __shared__ __align__(16) unsigned short Bs[BN*BKK];
  int m0 = blockIdx.x * BM, n0 = blockIdx.y * BN;
  f32x4 acc[4][4];
  #pragma unroll
  for (int m = 0; m < 4; ++m)
    #pragma unroll
    for (int n = 0; n < 4; ++n) acc[m][n] = 0.0f;
  gemm_core(x1, W1T, DMODEL, m0, n0, As, Bs, acc);
  const int lane = threadIdx.x & 63;
  const int w = threadIdx.x >> 6; const int wr = w >> 1, wc = w & 1;
  #pragma unroll
  for (int m = 0; m < 4; ++m) {
    #pragma unroll
    for (int n = 0; n < 4; ++n) {
      int col = n0 + wc*64 + n*16 + (lane & 15);
      float bval = b1[col];
      #pragma unroll
      for (int i = 0; i < 4; ++i) {
        int row = m0 + wr*64 + m*16 + (lane >> 4)*4 + i;
        h[(size_t)row * FFDIM + col] = f32_to_bf16(fmaxf(acc[m][n][i] + bval, 0.0f));
      }
    }
  }
}

// ---------------- FFN2: x += h @ W2 + b2  (64x64 tiles -> 512 blocks) ----------------
__global__ __launch_bounds__(256) void k_gemm_ffn2(
    const unsigned short* __restrict__ h, const unsigned short* __restrict__ W2T,
    const float* __restrict__ b2, float* __restrict__ x) {
  __shared__ __align__(16) unsigned short As[64*BKK];
  __shared__ __align__(16) unsigned short Bs[64*BKK];
  const int tid = threadIdx.x;
  const int lane = tid & 63;
  const int w = tid >> 6;
  const int wr = w >> 1, wc = w & 1;
  const int l15 = lane & 15;
  const int ko = (lane >> 4) * 8;
  const int rl = lane >> 2;
  const int cc = (lane & 3) * 8;
  const int m0 = blockIdx.x * 64, n0 = blockIdx.y * 64;
  f32x4 acc[2][2];
  #pragma unroll
  for (int m = 0; m < 2; ++m)
    #pragma unroll
    for (int n = 0; n < 2; ++n) acc[m][n] = 0.0f;
  for (int kb = 0; kb < FFDIM; kb += BKK) {
    int r0 = w * 16;                   // wave-uniform 16-row chunk
    gload16(h   + (size_t)(m0 + r0 + rl) * FFDIM + kb + cc, As + r0 * BKK);
    gload16(W2T + (size_t)(n0 + r0 + rl) * FFDIM + kb + cc, Bs + r0 * BKK);
    __syncthreads();
    u16x8 af[2], bfr[2];
    #pragma unroll
    for (int m = 0; m < 2; ++m) af[m]  = *(const u16x8*)(As + (wr*32 + m*16 + l15) * BKK + ko);
    #pragma unroll
    for (int n = 0; n < 2; ++n) bfr[n] = *(const u16x8*)(Bs + (wc*32 + n*16 + l15) * BKK + ko);
    #pragma unroll
    for (int m = 0; m < 2; ++m)
      #pragma unroll
      for (int n = 0; n < 2; ++n)
        acc[m][n] = mfma_bf16(af[m], bfr[n], acc[m][n]);
    __syncthreads();
  }
  const int g = lane >> 4;
  #pragma unroll
  for (int m = 0; m < 2; ++m) {
    #pragma unroll
    for (int n = 0; n < 2; ++n) {
      int col = n0 + wc*32 + n*16 + l15;
      float bval = b2[col];
      #pragma unroll
      for (int i = 0; i < 4; ++i) {
        int row = m0 + wr*32 + m*16 + g*4 + i;
        size_t idx = (size_t)row * DMODEL + col;
        x[idx] = x[idx] + acc[m][n][i] + bval;
      }
    }
  }
}

// ---------------- MFMA flash attention: 4 waves/block, 64 queries/block ----------------
#define KVBLK 64
#define KP 72   /* LDS pitch (ushorts): 144B -> 2-way conflicts only */

__global__ __launch_bounds__(256) void k_attn_mfma(
    const unsigned short* __restrict__ qb,   // [BH][S][DH]
    const unsigned short* __restrict__ kb,   // [BH][S][DH]
    const unsigned short* __restrict__ vtb,  // [BH][DH][S]
    float* __restrict__ x) {
  __shared__ __align__(16) unsigned short Kl[KVBLK*KP];
  __shared__ __align__(16) unsigned short Vl[DHEAD*KP];     // V^T tile: [dh][kv]
  __shared__ __align__(16) unsigned short Pl[4*16*KP];
  const int tid = threadIdx.x;
  const int w = tid >> 6, lane = tid & 63;
  const int c = lane & 15, g = lane >> 4;
  const int bh = blockIdx.x, qt = blockIdx.y;
  const int qw = qt * 64 + w * 16;          // this wave's first q row

  u16x8 qf[2];
  {
    const unsigned short* qrow = qb + ((size_t)bh * SEQ + qw + c) * DHEAD;
    qf[0] = *(const u16x8*)(qrow + g * 8);
    qf[1] = *(const u16x8*)(qrow + 32 + g * 8);
  }
  f32x4 aco[4];
  #pragma unroll
  for (int n = 0; n < 4; ++n) aco[n] = 0.0f;
  float m_i[4] = {-1e30f, -1e30f, -1e30f, -1e30f};
  float l_i[4] = {0.f, 0.f, 0.f, 0.f};

  const unsigned short* kbase = kb + (size_t)bh * SEQ * DHEAD;
  const unsigned short* vbase = vtb + (size_t)bh * DHEAD * SEQ;

  for (int kv0 = 0; kv0 < SEQ; kv0 += KVBLK) {
    #pragma unroll
    for (int i = 0; i < 2; ++i) {
      int idx = tid + i * 256;
      int r = idx >> 3, cb = (idx & 7) * 8;
      *(u16x8*)(Kl + r * KP + cb) = *(const u16x8*)(kbase + (size_t)(kv0 + r) * DHEAD + cb);
      *(u16x8*)(Vl + r * KP + cb) = *(const u16x8*)(vbase + (size_t)r * SEQ + kv0 + cb);
    }
    __syncthreads();

    f32x4 s[4];
    #pragma unroll
    for (int n = 0; n < 4; ++n) s[n] = 0.0f;
    #pragma unroll
    for (int n = 0; n < 4; ++n) {
      #pragma unroll
      for (int kk = 0; kk < 2; ++kk) {
        u16x8 kf = *(const u16x8*)(Kl + (n * 16 + c) * KP + kk * 32 + g * 8);
        s[n] = mfma_bf16(qf[kk], kf, s[n]);
      }
    }

    float corr_i[4];
    #pragma unroll
    for (int i = 0; i < 4; ++i) {
      float v0 = s[0][i] * 0.125f, v1 = s[1][i] * 0.125f;
      float v2 = s[2][i] * 0.125f, v3 = s[3][i] * 0.125f;
      float mx = fmaxf(fmaxf(v0, v1), fmaxf(v2, v3));
      mx = fmaxf(mx, __shfl_xor(mx, 1));
      mx = fmaxf(mx, __shfl_xor(mx, 2));
      mx = fmaxf(mx, __shfl_xor(mx, 4));
      mx = fmaxf(mx, __shfl_xor(mx, 8));
      float mn = fmaxf(m_i[i], mx);
      corr_i[i] = __expf(m_i[i] - mn);
      float p0 = __expf(v0 - mn), p1 = __expf(v1 - mn);
      float p2 = __expf(v2 - mn), p3 = __expf(v3 - mn);
      float ps = (p0 + p1) + (p2 + p3);
      ps += __shfl_xor(ps, 1);
      ps += __shfl_xor(ps, 2);
      ps += __shfl_xor(ps, 4);
      ps += __shfl_xor(ps, 8);
      l_i[i] = l_i[i] * corr_i[i] + ps;
      m_i[i] = mn;
      int prow = (w * 16 + g * 4 + i) * KP + c;
      Pl[prow]      = f32_to_bf16(p0);
      Pl[prow + 16] = f32_to_bf16(p1);
      Pl[prow + 32] = f32_to_bf16(p2);
      Pl[prow + 48] = f32_to_bf16(p3);
    }
    #pragma unroll
    for (int n = 0; n < 4; ++n)
      #pragma unroll
      for (int i = 0; i < 4; ++i) aco[n][i] *= corr_i[i];

    u16x8 pa[2];
    pa[0] = *(const u16x8*)(Pl + (w * 16 + c) * KP + g * 8);
    pa[1] = *(const u16x8*)(Pl + (w * 16 + c) * KP + 32 + g * 8);
    #pragma unroll
    for (int n = 0; n < 4; ++n) {
      #pragma unroll
      for (int kk = 0; kk < 2; ++kk) {
        u16x8 vf = *(const u16x8*)(Vl + (n * 16 + c) * KP + kk * 32 + g * 8);
        aco[n] = mfma_bf16(pa[kk], vf, aco[n]);
      }
    }
    __syncthreads();
  }

  const int b = bh >> 3, h = bh & 7;
  #pragma unroll
  for (int i = 0; i < 4; ++i) {
    float inv = 1.0f / l_i[i];
    int q = qw + g * 4 + i;
    float* xr = x + ((size_t)b * SEQ + q) * DMODEL + h * DHEAD;
    #pragma unroll
    for (int n = 0; n < 4; ++n)
      xr[n * 16 + c] += aco[n][i] * inv;
  }
}

// ---------------- host launch ----------------
extern "C" void kernel_launch(void* const* d_in, const int* in_sizes, int n_in,
                              void* d_out, int out_size, void* d_ws, size_t ws_size,
                              hipStream_t stream) {
  const float* src  = (const float*)d_in[0];
  const float* pos  = (const float*)d_in[1];
  const float* Wq   = (const float*)d_in[2];
  const float* bq   = (const float*)d_in[3];
  const float* Wk   = (const float*)d_in[4];
  const float* bk   = (const float*)d_in[5];
  const float* Wv   = (const float*)d_in[6];
  const float* bv   = (const float*)d_in[7];
  const float* W1   = (const float*)d_in[8];
  const float* b1   = (const float*)d_in[9];
  const float* W2   = (const float*)d_in[10];
  const float* b2   = (const float*)d_in[11];
  const float* ln1g = (const float*)d_in[12];
  const float* ln1b = (const float*)d_in[13];
  const float* ln2g = (const float*)d_in[14];
  const float* ln2b = (const float*)d_in[15];
  const float* lnfg = (const float*)d_in[16];
  const float* lnfb = (const float*)d_in[17];

  char* p = (char*)d_ws;
  float* x = (float*)p;                      p += (size_t)MROWS * DMODEL * 4;   // 8 MB
  unsigned short* x1 = (unsigned short*)p;   p += (size_t)MROWS * DMODEL * 2;   // 4 MB
  unsigned short* qb = (unsigned short*)p;   p += (size_t)MROWS * DMODEL * 2;
  unsigned short* kbuf = (unsigned short*)p; p += (size_t)MROWS * DMODEL * 2;
  unsigned short* vtbuf = (unsigned short*)p; p += (size_t)MROWS * DMODEL * 2;  // V^T [B,H,DH,S]
  unsigned short* hbuf = (unsigned short*)p; p += (size_t)MROWS * FFDIM * 2;    // 16 MB
  unsigned short* WqT = (unsigned short*)p;  p += (size_t)L_LAYERS * DMODEL * DMODEL * 2;
  unsigned short* WkT = (unsigned short*)p;  p += (size_t)L_LAYERS * DMODEL * DMODEL * 2;
  unsigned short* WvT = (unsigned short*)p;  p += (size_t)L_LAYERS * DMODEL * DMODEL * 2;
  unsigned short* W1T = (unsigned short*)p;  p += (size_t)L_LAYERS * DMODEL * FFDIM * 2;
  unsigned short* W2T = (unsigned short*)p;  p += (size_t)L_LAYERS * DMODEL * FFDIM * 2;

  // one-time weight transpose+convert
  k_transpose<<<dim3(16,16,6), 256, 0, stream>>>(Wq, WqT, DMODEL, DMODEL);
  k_transpose<<<dim3(16,16,6), 256, 0, stream>>>(Wk, WkT, DMODEL, DMODEL);
  k_transpose<<<dim3(16,16,6), 256, 0, stream>>>(Wv, WvT, DMODEL, DMODEL);
  k_transpose<<<dim3(64,16,6), 256, 0, stream>>>(W1, W1T, DMODEL, FFDIM);
  k_transpose<<<dim3(16,64,6), 256, 0, stream>>>(W2, W2T, FFDIM, DMODEL);

  for (int l = 0; l < L_LAYERS; ++l) {
    if (l == 0)
      k_addpos_ln<<<1024, 256, 0, stream>>>(src, pos, ln1g, ln1b, x, x1);
    else
      k_ln_bf16<<<1024, 256, 0, stream>>>(x, ln1g + l*DMODEL, ln1b + l*DMODEL, x1);
    k_gemm_qkv<<<dim3(32,24), 256, 0, stream>>>(
        x1,
        WqT + (size_t)l*DMODEL*DMODEL, WkT + (size_t)l*DMODEL*DMODEL, WvT + (size_t)l*DMODEL*DMODEL,
        bq + l*DMODEL, bk + l*DMODEL, bv + l*DMODEL,
        qb, kbuf, vtbuf);
    k_attn_mfma<<<dim3(32,16), 256, 0, stream>>>(qb, kbuf, vtbuf, x);
    k_ln_bf16<<<1024, 256, 0, stream>>>(x, ln2g + l*DMODEL, ln2b + l*DMODEL, x1);
    k_gemm_ffn1<<<dim3(32,16), 256, 0, stream>>>(x1, W1T + (size_t)l*DMODEL*FFDIM, b1 + l*FFDIM, hbuf);
    k_gemm_ffn2<<<dim3(64,8), 256, 0, stream>>>(hbuf, W2T + (size_t)l*DMODEL*FFDIM, b2 + l*DMODEL, x);
  }
  k_ln_final<<<1024, 256, 0, stream>>>(x, lnfg, lnfb, (float*)d_out);
}